// Round 13
// baseline (250.068 us; speedup 1.0000x reference)
//
#include <hip/hip_runtime.h>
#include <hip/hip_bf16.h>
#include <math.h>

#define N_NODES 51200
#define N_EDGES 614400
#define N_GRAPHS 256
#define T_CAPS 8
#define D_DIM 128
#define BN_EPS 1e-5f
#define MAXC 512     // routing chunk size
#define NBUCK 200    // buckets of 256 nodes (col>>8)
#define BCAP 4096    // edges per bucket capacity (mean 3072, sd 55)
#define EPB 2048     // edges per scatter block (256 thr x 8)

__device__ inline float waveReduceSum(float v) {
#pragma unroll
  for (int off = 1; off < 64; off <<= 1) v += __shfl_xor(v, off, 64);
  return v;
}
__device__ inline float bf_lo(unsigned u) { return __uint_as_float(u << 16); }
__device__ inline float bf_hi(unsigned u) { return __uint_as_float(u & 0xffff0000u); }
__device__ inline unsigned bfbits(float f) {
  unsigned u = __float_as_uint(f);
  return (u + 0x7FFFu + ((u >> 16) & 1u)) >> 16;  // RNE bf16 bits
}

// ---- K1: scatter (0..299) || xstats via bsearch (300..555) || W pack + bounds (556..811) ----
__global__ void __launch_bounds__(256) scatter_wx(
    const int* __restrict__ row, const int* __restrict__ col, const float* __restrict__ ew,
    int* __restrict__ bcur, uint2* __restrict__ ebuck, const float* __restrict__ x,
    const int* __restrict__ batch, const float* __restrict__ W, float* __restrict__ rawxsum,
    float* __restrict__ rawxsq, int* __restrict__ start, unsigned* __restrict__ Wp,
    unsigned* __restrict__ WTp) {
  int bid = blockIdx.x, tid = threadIdx.x;
  if (bid < 300) {  // ---- LDS-bucketed edge scatter ----
    __shared__ uint2 staged[EPB];  // 16 KB
    __shared__ int hcnt[256], lbase[256], gbase[256], scant[256];
    unsigned rx[8], ry[8];
    int bk[8], idx[8];
    int e0 = bid * EPB + tid;
#pragma unroll
    for (int k = 0; k < 8; k++) {
      int e = e0 + k * 256;
      int c = col[e];
      rx[k] = ((unsigned)c << 16) | (unsigned)row[e];
      ry[k] = bfbits(ew[e]);
      bk[k] = c >> 8;
    }
    hcnt[tid] = 0;
    __syncthreads();
#pragma unroll
    for (int k = 0; k < 8; k++) idx[k] = atomicAdd(&hcnt[bk[k]], 1);
    __syncthreads();
    int v = hcnt[tid];
    scant[tid] = v;
    __syncthreads();
    for (int off = 1; off < 256; off <<= 1) {
      int u = (tid >= off) ? scant[tid - off] : 0;
      __syncthreads();
      scant[tid] += u;
      __syncthreads();
    }
    lbase[tid] = scant[tid] - v;
    __syncthreads();
#pragma unroll
    for (int k = 0; k < 8; k++) staged[lbase[bk[k]] + idx[k]] = make_uint2(rx[k], ry[k]);
    if (tid < NBUCK) gbase[tid] = atomicAdd(&bcur[tid], hcnt[tid]);
    __syncthreads();
    for (int i = tid; i < EPB; i += 256) {
      uint2 r = staged[i];
      int b = r.x >> 24;
      int pos = gbase[b] + (i - lbase[b]);
      if (pos < BCAP) ebuck[b * BCAP + pos] = r;
    }
    return;
  }
  if (bid < 556) {  // ---- per-graph x stats; bounds by binary search on sorted batch ----
    int g = bid - 300;
    int lo = 0, hi = N_NODES;  // lower_bound(batch, g)
    while (lo < hi) {
      int mid = (lo + hi) >> 1;
      if (batch[mid] < g) lo = mid + 1; else hi = mid;
    }
    int st = lo;
    hi = N_NODES;  // lower_bound(batch, g+1)
    while (lo < hi) {
      int mid = (lo + hi) >> 1;
      if (batch[mid] < g + 1) lo = mid + 1; else hi = mid;
    }
    int en = lo;
    __shared__ float ls[256], ls2[256];
    int d = tid & 127, h = tid >> 7;
    float s = 0.f, s2 = 0.f;
    for (int n = st + h; n < en; n += 2) {
      float v = x[n * D_DIM + d];
      s += v;
      s2 += v * v;
    }
    ls[tid] = s;
    ls2[tid] = s2;
    __syncthreads();
    if (h == 0) {
      rawxsum[g * D_DIM + d] = ls[d] + ls[d + 128];
      rawxsq[g * D_DIM + d] = ls2[d] + ls2[d + 128];
    }
    return;
  }
  // ---- bf16-pack W (Wp: 2 dd per dword; WTp: 2 oo per dword) + graph bounds ----
  int i = (bid - 556) * 256 + tid;  // [0, 65536)
  {
    int t = i >> 13, r = i & 8191;
    int k = r >> 7, o = r & 127;
    float a = W[(t << 14) + (k << 8) + o];
    float b = W[(t << 14) + (k << 8) + 128 + o];
    Wp[i] = bfbits(a) | (bfbits(b) << 16);
    float2 w2 = ((const float2*)W)[(t << 13) + (o << 6) + k];
    WTp[i] = bfbits(w2.x) | (bfbits(w2.y) << 16);
  }
  if (i < N_NODES) {
    int bn = batch[i];
    if (i == 0) {
      for (int g = 0; g <= bn; g++) start[g] = 0;
    } else {
      int bp = batch[i - 1];
      for (int g = bp + 1; g <= bn; g++) start[g] = i;
    }
    if (i == N_NODES - 1)
      for (int g = bn + 1; g <= N_GRAPHS; g++) start[g] = N_NODES;
  }
}

// ---- K2: per-bucket counting sort -> CSR + inline BN + deg/dis + y (one block/bucket) ----
__global__ void __launch_bounds__(256) build(const uint2* __restrict__ ebuck,
                                             const int* __restrict__ bcur,
                                             const float* __restrict__ rawxsum,
                                             const float* __restrict__ rawxsq,
                                             const float* __restrict__ gamma,
                                             const float* __restrict__ beta,
                                             unsigned* __restrict__ csr,
                                             int* __restrict__ nstart, int* __restrict__ ncnt,
                                             const float* __restrict__ x,
                                             float* __restrict__ scale,
                                             float* __restrict__ shift,
                                             float* __restrict__ dis,
                                             __hip_bfloat162* __restrict__ y) {
  int b = blockIdx.x, tid = threadIdx.x;
  __shared__ uint2 staged[BCAP];   // 32 KB
  __shared__ unsigned outr[BCAP];  // 16 KB
  __shared__ int hist[256], pref[256], cur[256], scant[256];
  __shared__ float dis_l[256];
  __shared__ float sc_l[128], sh_l[128];
  // inline BN: redundant per-block reduction of rawxsum/rawxsq over graphs
  {
    int d = tid & 127, h = tid >> 7;
    float s = 0.f, s2 = 0.f;
    for (int g = h; g < N_GRAPHS; g += 2) {
      s += rawxsum[g * D_DIM + d];
      s2 += rawxsq[g * D_DIM + d];
    }
    // reuse hist/pref LDS as float scratch before the sort uses them
    ((float*)hist)[tid] = s;
    ((float*)pref)[tid] = s2;
    __syncthreads();
    if (h == 0) {
      float st_ = ((float*)hist)[d] + ((float*)hist)[d + 128];
      float sq_ = ((float*)pref)[d] + ((float*)pref)[d + 128];
      float mu = st_ * (1.0f / N_NODES);
      float var = sq_ * (1.0f / N_NODES) - mu * mu;
      float rstd = rsqrtf(var + BN_EPS);
      float sc = gamma[d] * rstd;
      sc_l[d] = sc;
      sh_l[d] = beta[d] - mu * sc;
      if (b == 0) {  // publish for routing's x_mean reconstruction
        scale[d] = sc;
        shift[d] = sh_l[d];
      }
    }
  }
  __syncthreads();
  int cnt = min(bcur[b], BCAP);
  for (int i = tid; i < cnt; i += 256) staged[i] = ebuck[b * BCAP + i];
  hist[tid] = 0;
  __syncthreads();
  for (int i = tid; i < cnt; i += 256) {
    int dl = (staged[i].x >> 16) & 255;
    atomicAdd(&hist[dl], 1);
  }
  __syncthreads();
  int v = hist[tid];
  scant[tid] = v;
  __syncthreads();
  for (int off = 1; off < 256; off <<= 1) {
    int u = (tid >= off) ? scant[tid - off] : 0;
    __syncthreads();
    scant[tid] += u;
    __syncthreads();
  }
  pref[tid] = scant[tid] - v;
  cur[tid] = pref[tid];
  __syncthreads();
  for (int i = tid; i < cnt; i += 256) {
    uint2 r = staged[i];
    int dl = (r.x >> 16) & 255;
    int p = atomicAdd(&cur[dl], 1);
    outr[p] = ((r.x & 0xFFFFu) << 16) | r.y;  // (src:16 | bf16(ew):16)
  }
  __syncthreads();
  for (int i = tid; i < cnt; i += 256) csr[b * BCAP + i] = outr[i];
  int n = b * 256 + tid;
  int p0 = pref[tid], hc = hist[tid];
  nstart[n] = b * BCAP + p0;
  ncnt[n] = hc;
  float s = 0.f;
  for (int j = p0; j < p0 + hc; j++) s += bf_lo(outr[j]);
  float dv = s + 1.0f;  // + self-loop weight
  float dn = dv > 0.f ? rsqrtf(fmaxf(dv, 1e-12f)) : 0.f;
  dis[n] = dn;
  dis_l[tid] = dn;
  __syncthreads();
  const float2* x2 = (const float2*)x;
  const float2* sc2 = (const float2*)sc_l;
  const float2* sh2 = (const float2*)sh_l;
  for (int i = tid; i < 256 * 64; i += 256) {
    int nl = i >> 6, l = i & 63;
    float dnl = dis_l[nl];
    float2 scv = sc2[l], shv = sh2[l];
    float2 xv = x2[(b * 256 + nl) * 64 + l];
    float2 yv;
    yv.x = dnl * (xv.x * scv.x + shv.x);
    yv.y = dnl * (xv.y * scv.y + shv.y);
    y[(b * 256 + nl) * 64 + l] = __float22bfloat162_rn(yv);
  }
}

// ---- K3: wave per node: agg[n] = bf16( dis[n]*(y[n] + sum_e ew_e*y[src_e]) ) ----
__global__ void __launch_bounds__(256) node_gather(const __hip_bfloat162* __restrict__ y,
                                                   const float* __restrict__ dis,
                                                   const int* __restrict__ nstart,
                                                   const int* __restrict__ ncnt,
                                                   const unsigned* __restrict__ csr,
                                                   __hip_bfloat162* __restrict__ agg) {
  int n = blockIdx.x * 4 + (threadIdx.x >> 6);
  int lane = threadIdx.x & 63;
  int st = nstart[n], c = ncnt[n];
  float2 a = __bfloat1622float2(y[n * 64 + lane]);  // self term
  int j = 0;
  for (; j + 4 <= c; j += 4) {
    unsigned r0 = csr[st + j], r1 = csr[st + j + 1], r2 = csr[st + j + 2],
             r3 = csr[st + j + 3];
    float2 v0 = __bfloat1622float2(y[(r0 >> 16) * 64 + lane]);
    float2 v1 = __bfloat1622float2(y[(r1 >> 16) * 64 + lane]);
    float2 v2 = __bfloat1622float2(y[(r2 >> 16) * 64 + lane]);
    float2 v3 = __bfloat1622float2(y[(r3 >> 16) * 64 + lane]);
    float w0 = bf_lo(r0), w1 = bf_lo(r1), w2 = bf_lo(r2), w3 = bf_lo(r3);
    a.x += w0 * v0.x + w1 * v1.x + w2 * v2.x + w3 * v3.x;
    a.y += w0 * v0.y + w1 * v1.y + w2 * v2.y + w3 * v3.y;
  }
  for (; j < c; j++) {
    unsigned r = csr[st + j];
    float2 v = __bfloat1622float2(y[(r >> 16) * 64 + lane]);
    float w = bf_lo(r);
    a.x += w * v.x;
    a.y += w * v.y;
  }
  float dn = dis[n];
  a.x *= dn;
  a.y *= dn;
  agg[n * 64 + lane] = __float22bfloat162_rn(a);
}

// ---- K4: routing v4: bf16-packed W GEMVs, squash-fold (no scale phase), telescoped wv/bv ----
__global__ void __launch_bounds__(1024) routing_fused(
    const unsigned* __restrict__ agg_bf, const int* __restrict__ start,
    const unsigned* __restrict__ Wp, const unsigned* __restrict__ WTp,
    const float* __restrict__ bias, const float* __restrict__ rawxsum,
    const float* __restrict__ scale, const float* __restrict__ shift,
    float* __restrict__ out) {
  int g = blockIdx.x;
  int tid = threadIdx.x;
  int st = start[g], c = start[g + 1] - st;

  __shared__ float dt_sh[MAXC][T_CAPS];
  __shared__ float ac_sh[T_CAPS][D_DIM];
  __shared__ float s_sh[T_CAPS][D_DIM];
  __shared__ float wv_sh[T_CAPS][132];
  __shared__ float csum_sh[T_CAPS], bv_sh[T_CAPS], f_sh[T_CAPS], s2p[T_CAPS][2];
  __shared__ float csp_sh[32];

  float* scratch = &dt_sh[0][0];
  const uint2* aggb2 = (const uint2*)agg_bf;
  const uint4* aggb4 = (const uint4*)agg_bf;

  for (int i = tid; i < T_CAPS * 132; i += 1024) (&wv_sh[0][0])[i] = 0.f;
  if (tid < T_CAPS) {
    bv_sh[tid] = 0.f;
    csum_sh[tid] = 0.125f * (float)c;
  }
  {
    int d2 = tid & 63, h = tid >> 6;
    float sx = 0.f, sy = 0.f;
    for (int n = st + h; n < st + c; n += 16) {
      unsigned u = agg_bf[n * 64 + d2];
      sx += bf_lo(u);
      sy += bf_hi(u);
    }
    scratch[h * 128 + d2 * 2] = sx;
    scratch[h * 128 + d2 * 2 + 1] = sy;
  }
  __syncthreads();
  if (tid < 128) {
    float s = 0.f;
#pragma unroll
    for (int h = 0; h < 16; h++) s += scratch[h * 128 + tid];
    s *= 0.125f;
#pragma unroll
    for (int t = 0; t < T_CAPS; t++) ac_sh[t][tid] = s;
  }
  __syncthreads();

  int tG = tid >> 7, oG = tid & 127;
  int nL = tid >> 3, tL = tid & 7;
  int tA = tid >> 7, rep = (tid >> 5) & 3, l32 = tid & 31;

  for (int iter = 0; iter < 3; iter++) {
    {  // GEMV1: s[t][o] = ac·W[t][:,o] + csum*bias (+ x_mean last iter); bf16-packed W
      const unsigned* Wpt = Wp + (tG << 13);
      float s = 0.f;
#pragma unroll 8
      for (int k = 0; k < 64; k++) {
        unsigned u = Wpt[(k << 7) + oG];
        s += ac_sh[tG][2 * k] * bf_lo(u) + ac_sh[tG][2 * k + 1] * bf_hi(u);
      }
      s += csum_sh[tG] * bias[(tG << 7) + oG];
      if (iter == 2) {
        float cf = (float)c;
        float ic = 1.0f / fmaxf(cf, 1.0f);
        s += (scale[oG] * rawxsum[g * D_DIM + oG] + cf * shift[oG]) * ic;
      }
      s_sh[tG][oG] = s;
      float p = waveReduceSum(s * s);
      if ((tid & 63) == 0) s2p[tG][(tid >> 6) & 1] = p;
    }
    __syncthreads();
    if (tid < T_CAPS) {
      float s2 = s2p[tid][0] + s2p[tid][1];
      float f = (s2 / (1.0f + s2)) * rsqrtf(s2 + 1e-16f);
      f_sh[tid] = f;
      if (iter == 2) out[g * T_CAPS + tid] = sqrtf(f * f * s2 + 1e-16f);
    }
    __syncthreads();
    if (iter == 2) return;
    {  // GEMV2 on raw s, squash factor folded at write: wv += f*(WT·s), bv += f*(bias·s)
      const unsigned* WTpt = WTp + (tG << 13);
      float s = 0.f;
#pragma unroll 8
      for (int k = 0; k < 64; k++) {
        unsigned u = WTpt[(k << 7) + oG];
        s += s_sh[tG][2 * k] * bf_lo(u) + s_sh[tG][2 * k + 1] * bf_hi(u);
      }
      wv_sh[tG][oG] += f_sh[tG] * s;
      float bp = bias[(tG << 7) + oG] * s_sh[tG][oG];
      bp = waveReduceSum(bp);
      if ((tid & 63) == 0) s2p[tG][(tid >> 6) & 1] = bp;
    }
    __syncthreads();
    if (tid < T_CAPS) bv_sh[tid] += f_sh[tid] * (s2p[tid][0] + s2p[tid][1]);
    __syncthreads();

    float4 acc = make_float4(0.f, 0.f, 0.f, 0.f);
    float cslr = 0.f;
    for (int cb = 0; cb < c; cb += MAXC) {
      int nv = min(MAXC, c - cb);
      for (int n = nL; n < nv; n += 128) {
        const uint4* rowp = aggb4 + (size_t)(st + cb + n) * 16;
        float pr = 0.f;
#pragma unroll 4
        for (int k = 0; k < 16; k++) {
          uint4 u = rowp[k];
          float4 wa = *(const float4*)&wv_sh[tL][k * 8];
          float4 wb = *(const float4*)&wv_sh[tL][k * 8 + 4];
          pr += bf_lo(u.x) * wa.x + bf_hi(u.x) * wa.y + bf_lo(u.y) * wa.z + bf_hi(u.y) * wa.w;
          pr += bf_lo(u.z) * wb.x + bf_hi(u.z) * wb.y + bf_lo(u.w) * wb.z + bf_hi(u.w) * wb.w;
        }
        dt_sh[n][tL] = pr + bv_sh[tL];
      }
      __syncthreads();
      if (tid < nv) {
        float l0 = dt_sh[tid][0], l1 = dt_sh[tid][1], l2 = dt_sh[tid][2], l3 = dt_sh[tid][3];
        float l4 = dt_sh[tid][4], l5 = dt_sh[tid][5], l6 = dt_sh[tid][6], l7 = dt_sh[tid][7];
        float m = fmaxf(fmaxf(fmaxf(l0, l1), fmaxf(l2, l3)),
                        fmaxf(fmaxf(l4, l5), fmaxf(l6, l7)));
        float e0 = __expf(l0 - m), e1 = __expf(l1 - m), e2 = __expf(l2 - m),
              e3 = __expf(l3 - m), e4 = __expf(l4 - m), e5 = __expf(l5 - m),
              e6 = __expf(l6 - m), e7 = __expf(l7 - m);
        float iz = 1.0f / (e0 + e1 + e2 + e3 + e4 + e5 + e6 + e7);
        dt_sh[tid][0] = e0 * iz;
        dt_sh[tid][1] = e1 * iz;
        dt_sh[tid][2] = e2 * iz;
        dt_sh[tid][3] = e3 * iz;
        dt_sh[tid][4] = e4 * iz;
        dt_sh[tid][5] = e5 * iz;
        dt_sh[tid][6] = e6 * iz;
        dt_sh[tid][7] = e7 * iz;
      }
      __syncthreads();
      for (int nj = rep; nj < nv; nj += 4) {
        float cj = dt_sh[nj][tA];
        uint2 u = aggb2[(size_t)(st + cb + nj) * 32 + l32];
        acc.x += cj * bf_lo(u.x);
        acc.y += cj * bf_hi(u.x);
        acc.z += cj * bf_lo(u.y);
        acc.w += cj * bf_hi(u.y);
        if (l32 == 0) cslr += cj;
      }
      __syncthreads();
    }
    int d4 = l32 << 2;
    if (rep > 0) *(float4*)&scratch[(((rep - 1) << 3) + tA) * 128 + d4] = acc;
    if (l32 == 0) csp_sh[tid >> 5] = cslr;
    __syncthreads();
    if (rep == 0) {
#pragma unroll
      for (int m = 0; m < 3; m++) {
        float4 o4 = *(const float4*)&scratch[((m << 3) + tA) * 128 + d4];
        acc.x += o4.x;
        acc.y += o4.y;
        acc.z += o4.z;
        acc.w += o4.w;
      }
      *(float4*)&ac_sh[tA][d4] = acc;
    }
    if (tid < T_CAPS)
      csum_sh[tid] = csp_sh[tid * 4] + csp_sh[tid * 4 + 1] + csp_sh[tid * 4 + 2] +
                     csp_sh[tid * 4 + 3];
    __syncthreads();
  }
}

extern "C" void kernel_launch(void* const* d_in, const int* in_sizes, int n_in, void* d_out,
                              int out_size, void* d_ws, size_t ws_size, hipStream_t stream) {
  const float* x = (const float*)d_in[0];
  const float* ew = (const float*)d_in[1];
  const float* gamma = (const float*)d_in[2];
  const float* beta = (const float*)d_in[3];
  const float* W = (const float*)d_in[4];
  const float* bias = (const float*)d_in[5];
  const int* eidx = (const int*)d_in[6];
  const int* batch = (const int*)d_in[7];
  float* out = (float*)d_out;
  float* w = (float*)d_ws;

  const int* row = eidx;
  const int* col = eidx + N_EDGES;

  int* bcur = (int*)w;                         // 256 (200 used; memset)
  int* start = bcur + 256;                     // 260 (even pad)
  float* scale = (float*)(start + 260);        // 128
  float* shift = scale + 128;                  // 128
  float* dis = shift + 128;                    // N
  float* rawxsum = dis + N_NODES;              // 256*128
  float* rawxsq = rawxsum + N_GRAPHS * D_DIM;  // 256*128
  unsigned* Wp = (unsigned*)(rawxsq + N_GRAPHS * D_DIM);  // 65536 (256 KB)
  unsigned* WTp = Wp + 65536;                             // 65536
  int* nstart = (int*)(WTp + 65536);                      // N
  int* ncnt = nstart + N_NODES;                           // N
  uint2* ebuck = (uint2*)(ncnt + N_NODES);                // NBUCK*BCAP*8B
  unsigned* csr = (unsigned*)(ebuck + (size_t)NBUCK * BCAP);             // NBUCK*BCAP*4B
  __hip_bfloat162* y = (__hip_bfloat162*)(csr + (size_t)NBUCK * BCAP);   // N*64
  unsigned* agg_bf = (unsigned*)(y + (size_t)N_NODES * 64);              // N*64

  hipMemsetAsync(bcur, 0, 256 * sizeof(int), stream);
  scatter_wx<<<300 + 256 + 256, 256, 0, stream>>>(row, col, ew, bcur, ebuck, x, batch, W,
                                                  rawxsum, rawxsq, start, Wp, WTp);
  build<<<NBUCK, 256, 0, stream>>>(ebuck, bcur, rawxsum, rawxsq, gamma, beta, csr, nstart,
                                   ncnt, x, scale, shift, dis, y);
  node_gather<<<N_NODES / 4, 256, 0, stream>>>(y, dis, nstart, ncnt, csr,
                                               (__hip_bfloat162*)agg_bf);
  routing_fused<<<N_GRAPHS, 1024, 0, stream>>>(agg_bf, start, Wp, WTp, bias, rawxsum, scale,
                                               shift, out);
}

// Round 14
// 223.720 us; speedup vs baseline: 1.1178x; 1.1178x over previous
//
#include <hip/hip_runtime.h>
#include <hip/hip_bf16.h>
#include <math.h>

#define N_NODES 51200
#define N_EDGES 614400
#define N_GRAPHS 256
#define T_CAPS 8
#define D_DIM 128
#define BN_EPS 1e-5f
#define MAXC 512     // routing chunk size
#define NBUCK 200    // buckets of 256 nodes (col>>8)
#define BCAP 4096    // edges per bucket capacity (mean 3072, sd 55)
#define EPB 2048     // edges per scatter block (256 thr x 8)

__device__ inline float waveReduceSum(float v) {
#pragma unroll
  for (int off = 1; off < 64; off <<= 1) v += __shfl_xor(v, off, 64);
  return v;
}
__device__ inline float bf_lo(unsigned u) { return __uint_as_float(u << 16); }
__device__ inline float bf_hi(unsigned u) { return __uint_as_float(u & 0xffff0000u); }
__device__ inline unsigned bfbits(float f) {
  unsigned u = __float_as_uint(f);
  return (u + 0x7FFFu + ((u >> 16) & 1u)) >> 16;  // RNE bf16 bits
}

// ---- L1: zero bucket cursors + graph bounds (sorted batch) + bf16 W pack ----
__global__ void __launch_bounds__(256) prep(const int* __restrict__ batch,
                                            const float* __restrict__ W,
                                            int* __restrict__ start, int* __restrict__ bcur,
                                            unsigned* __restrict__ Wp,
                                            unsigned* __restrict__ WTp) {
  int i = blockIdx.x * 256 + threadIdx.x;  // 51200 threads
  if (i < NBUCK) bcur[i] = 0;
  int bn = batch[i];
  if (i == 0) {
    for (int g = 0; g <= bn; g++) start[g] = 0;
  } else {
    int bp = batch[i - 1];
    for (int g = bp + 1; g <= bn; g++) start[g] = i;
  }
  if (i == N_NODES - 1)
    for (int g = bn + 1; g <= N_GRAPHS; g++) start[g] = N_NODES;
  // pack W -> Wp (pairs along dd) and WTp (pairs along oo); 65536 dwords each
  for (int j = i; j < 65536; j += N_NODES) {
    int t = j >> 13, r = j & 8191;
    int k = r >> 7, o = r & 127;
    float a = W[(t << 14) + (k << 8) + o];
    float b = W[(t << 14) + (k << 8) + 128 + o];
    Wp[j] = bfbits(a) | (bfbits(b) << 16);
    float2 w2 = ((const float2*)W)[(t << 13) + (o << 6) + k];
    WTp[j] = bfbits(w2.x) | (bfbits(w2.y) << 16);
  }
}

// ---- L2: LDS-bucketed edge scatter (blocks 0..299) || per-graph xstats (300..555) ----
__global__ void __launch_bounds__(256) scatter_x(
    const int* __restrict__ row, const int* __restrict__ col, const float* __restrict__ ew,
    int* __restrict__ bcur, uint2* __restrict__ ebuck, const float* __restrict__ x,
    const int* __restrict__ start, float* __restrict__ rawxsum, float* __restrict__ rawxsq) {
  int bid = blockIdx.x, tid = threadIdx.x;
  if (bid < 300) {
    __shared__ uint2 staged[EPB];  // 16 KB
    __shared__ int hcnt[256], lbase[256], gbase[256], scant[256];
    unsigned rx[8], ry[8];
    int bk[8], idx[8];
    int e0 = bid * EPB + tid;
#pragma unroll
    for (int k = 0; k < 8; k++) {
      int e = e0 + k * 256;
      int c = col[e];
      rx[k] = ((unsigned)c << 16) | (unsigned)row[e];
      ry[k] = bfbits(ew[e]);
      bk[k] = c >> 8;
    }
    hcnt[tid] = 0;
    __syncthreads();
#pragma unroll
    for (int k = 0; k < 8; k++) idx[k] = atomicAdd(&hcnt[bk[k]], 1);
    __syncthreads();
    int v = hcnt[tid];
    scant[tid] = v;
    __syncthreads();
    for (int off = 1; off < 256; off <<= 1) {
      int u = (tid >= off) ? scant[tid - off] : 0;
      __syncthreads();
      scant[tid] += u;
      __syncthreads();
    }
    lbase[tid] = scant[tid] - v;
    __syncthreads();
#pragma unroll
    for (int k = 0; k < 8; k++) staged[lbase[bk[k]] + idx[k]] = make_uint2(rx[k], ry[k]);
    if (tid < NBUCK) gbase[tid] = atomicAdd(&bcur[tid], hcnt[tid]);
    __syncthreads();
    for (int i = tid; i < EPB; i += 256) {
      uint2 r = staged[i];
      int b = r.x >> 24;  // col>>8
      int pos = gbase[b] + (i - lbase[b]);
      if (pos < BCAP) ebuck[b * BCAP + pos] = r;
    }
    return;
  }
  int g = bid - 300;
  __shared__ float ls[256], ls2[256];
  int d = tid & 127, h = tid >> 7;
  int st = start[g], en = start[g + 1];
  float s = 0.f, s2 = 0.f;
  for (int n = st + h; n < en; n += 2) {
    float v = x[n * D_DIM + d];
    s += v;
    s2 += v * v;
  }
  ls[tid] = s;
  ls2[tid] = s2;
  __syncthreads();
  if (h == 0) {
    rawxsum[g * D_DIM + d] = ls[d] + ls[d + 128];
    rawxsq[g * D_DIM + d] = ls2[d] + ls2[d + 128];
  }
}

// ---- L3: BN finalize: one block per feature d ----
__global__ void __launch_bounds__(256) bn_fin(const float* __restrict__ rawxsum,
                                              const float* __restrict__ rawxsq,
                                              const float* __restrict__ gamma,
                                              const float* __restrict__ beta,
                                              float* __restrict__ scale,
                                              float* __restrict__ shift) {
  int d = blockIdx.x;
  int tid = threadIdx.x;
  __shared__ float ls[256], ls2[256];
  ls[tid] = rawxsum[tid * D_DIM + d];
  ls2[tid] = rawxsq[tid * D_DIM + d];
  __syncthreads();
  for (int off = 128; off; off >>= 1) {
    if (tid < off) {
      ls[tid] += ls[tid + off];
      ls2[tid] += ls2[tid + off];
    }
    __syncthreads();
  }
  if (tid == 0) {
    float mu = ls[0] * (1.0f / N_NODES);
    float var = ls2[0] * (1.0f / N_NODES) - mu * mu;
    float rstd = rsqrtf(var + BN_EPS);
    float sc = gamma[d] * rstd;
    scale[d] = sc;
    shift[d] = beta[d] - mu * sc;
  }
}

// ---- L4: per-bucket counting sort -> compact CSR + deg/dis + y (one block/bucket) ----
__global__ void __launch_bounds__(256) build(const uint2* __restrict__ ebuck,
                                             const int* __restrict__ bcur,
                                             unsigned* __restrict__ csr,
                                             int* __restrict__ nstart, int* __restrict__ ncnt,
                                             const float* __restrict__ x,
                                             const float* __restrict__ scale,
                                             const float* __restrict__ shift,
                                             float* __restrict__ dis,
                                             __hip_bfloat162* __restrict__ y) {
  int b = blockIdx.x, tid = threadIdx.x;
  __shared__ uint2 staged[BCAP];   // 32 KB
  __shared__ unsigned outr[BCAP];  // 16 KB
  __shared__ int hist[256], pref[256], cur[256], scant[256];
  __shared__ float dis_l[256];
  int cnt = min(bcur[b], BCAP);
  for (int i = tid; i < cnt; i += 256) staged[i] = ebuck[b * BCAP + i];
  hist[tid] = 0;
  __syncthreads();
  for (int i = tid; i < cnt; i += 256) {
    int dl = (staged[i].x >> 16) & 255;
    atomicAdd(&hist[dl], 1);
  }
  __syncthreads();
  int v = hist[tid];
  scant[tid] = v;
  __syncthreads();
  for (int off = 1; off < 256; off <<= 1) {
    int u = (tid >= off) ? scant[tid - off] : 0;
    __syncthreads();
    scant[tid] += u;
    __syncthreads();
  }
  pref[tid] = scant[tid] - v;
  cur[tid] = pref[tid];
  __syncthreads();
  for (int i = tid; i < cnt; i += 256) {
    uint2 r = staged[i];
    int dl = (r.x >> 16) & 255;
    int p = atomicAdd(&cur[dl], 1);
    outr[p] = ((r.x & 0xFFFFu) << 16) | r.y;  // (src:16 | bf16(ew):16)
  }
  __syncthreads();
  for (int i = tid; i < cnt; i += 256) csr[b * BCAP + i] = outr[i];
  int n = b * 256 + tid;
  int p0 = pref[tid], hc = hist[tid];
  nstart[n] = b * BCAP + p0;
  ncnt[n] = hc;
  float s = 0.f;
  for (int j = p0; j < p0 + hc; j++) s += bf_lo(outr[j]);
  float dv = s + 1.0f;  // + self-loop weight
  float dn = dv > 0.f ? rsqrtf(fmaxf(dv, 1e-12f)) : 0.f;
  dis[n] = dn;
  dis_l[tid] = dn;
  __syncthreads();
  const float2* x2 = (const float2*)x;
  const float2* sc2 = (const float2*)scale;
  const float2* sh2 = (const float2*)shift;
  for (int i = tid; i < 256 * 64; i += 256) {
    int nl = i >> 6, l = i & 63;
    float dnl = dis_l[nl];
    float2 scv = sc2[l], shv = sh2[l];
    float2 xv = x2[(b * 256 + nl) * 64 + l];
    float2 yv;
    yv.x = dnl * (xv.x * scv.x + shv.x);
    yv.y = dnl * (xv.y * scv.y + shv.y);
    y[(b * 256 + nl) * 64 + l] = __float22bfloat162_rn(yv);
  }
}

// ---- L5: wave per node: agg[n] = bf16( dis[n]*(y[n] + sum_e ew_e*y[src_e]) ) ----
__global__ void __launch_bounds__(256) node_gather(const __hip_bfloat162* __restrict__ y,
                                                   const float* __restrict__ dis,
                                                   const int* __restrict__ nstart,
                                                   const int* __restrict__ ncnt,
                                                   const unsigned* __restrict__ csr,
                                                   __hip_bfloat162* __restrict__ agg) {
  int n = blockIdx.x * 4 + (threadIdx.x >> 6);
  int lane = threadIdx.x & 63;
  int st = nstart[n], c = ncnt[n];
  float2 a = __bfloat1622float2(y[n * 64 + lane]);  // self term
  int j = 0;
  for (; j + 4 <= c; j += 4) {
    unsigned r0 = csr[st + j], r1 = csr[st + j + 1], r2 = csr[st + j + 2],
             r3 = csr[st + j + 3];
    float2 v0 = __bfloat1622float2(y[(r0 >> 16) * 64 + lane]);
    float2 v1 = __bfloat1622float2(y[(r1 >> 16) * 64 + lane]);
    float2 v2 = __bfloat1622float2(y[(r2 >> 16) * 64 + lane]);
    float2 v3 = __bfloat1622float2(y[(r3 >> 16) * 64 + lane]);
    float w0 = bf_lo(r0), w1 = bf_lo(r1), w2 = bf_lo(r2), w3 = bf_lo(r3);
    a.x += w0 * v0.x + w1 * v1.x + w2 * v2.x + w3 * v3.x;
    a.y += w0 * v0.y + w1 * v1.y + w2 * v2.y + w3 * v3.y;
  }
  for (; j < c; j++) {
    unsigned r = csr[st + j];
    float2 v = __bfloat1622float2(y[(r >> 16) * 64 + lane]);
    float w = bf_lo(r);
    a.x += w * v.x;
    a.y += w * v.y;
  }
  float dn = dis[n];
  a.x *= dn;
  a.y *= dn;
  agg[n * 64 + lane] = __float22bfloat162_rn(a);
}

// ---- L6: routing v4: bf16-packed W GEMVs, squash-fold, telescoped wv/bv ----
__global__ void __launch_bounds__(1024) routing_fused(
    const unsigned* __restrict__ agg_bf, const int* __restrict__ start,
    const unsigned* __restrict__ Wp, const unsigned* __restrict__ WTp,
    const float* __restrict__ bias, const float* __restrict__ rawxsum,
    const float* __restrict__ scale, const float* __restrict__ shift,
    float* __restrict__ out) {
  int g = blockIdx.x;
  int tid = threadIdx.x;
  int st = start[g], c = start[g + 1] - st;

  __shared__ float dt_sh[MAXC][T_CAPS];
  __shared__ float ac_sh[T_CAPS][D_DIM];
  __shared__ float s_sh[T_CAPS][D_DIM];
  __shared__ float wv_sh[T_CAPS][132];
  __shared__ float csum_sh[T_CAPS], bv_sh[T_CAPS], f_sh[T_CAPS], s2p[T_CAPS][2];
  __shared__ float csp_sh[32];

  float* scratch = &dt_sh[0][0];
  const uint2* aggb2 = (const uint2*)agg_bf;
  const uint4* aggb4 = (const uint4*)agg_bf;

  for (int i = tid; i < T_CAPS * 132; i += 1024) (&wv_sh[0][0])[i] = 0.f;
  if (tid < T_CAPS) {
    bv_sh[tid] = 0.f;
    csum_sh[tid] = 0.125f * (float)c;
  }
  {
    int d2 = tid & 63, h = tid >> 6;
    float sx = 0.f, sy = 0.f;
    for (int n = st + h; n < st + c; n += 16) {
      unsigned u = agg_bf[n * 64 + d2];
      sx += bf_lo(u);
      sy += bf_hi(u);
    }
    scratch[h * 128 + d2 * 2] = sx;
    scratch[h * 128 + d2 * 2 + 1] = sy;
  }
  __syncthreads();
  if (tid < 128) {
    float s = 0.f;
#pragma unroll
    for (int h = 0; h < 16; h++) s += scratch[h * 128 + tid];
    s *= 0.125f;
#pragma unroll
    for (int t = 0; t < T_CAPS; t++) ac_sh[t][tid] = s;
  }
  __syncthreads();

  int tG = tid >> 7, oG = tid & 127;
  int nL = tid >> 3, tL = tid & 7;
  int tA = tid >> 7, rep = (tid >> 5) & 3, l32 = tid & 31;

  for (int iter = 0; iter < 3; iter++) {
    {  // GEMV1: s[t][o] = ac·W[t][:,o] + csum*bias (+ x_mean last iter); bf16-packed W
      const unsigned* Wpt = Wp + (tG << 13);
      float s = 0.f;
#pragma unroll 8
      for (int k = 0; k < 64; k++) {
        unsigned u = Wpt[(k << 7) + oG];
        s += ac_sh[tG][2 * k] * bf_lo(u) + ac_sh[tG][2 * k + 1] * bf_hi(u);
      }
      s += csum_sh[tG] * bias[(tG << 7) + oG];
      if (iter == 2) {
        float cf = (float)c;
        float ic = 1.0f / fmaxf(cf, 1.0f);
        s += (scale[oG] * rawxsum[g * D_DIM + oG] + cf * shift[oG]) * ic;
      }
      s_sh[tG][oG] = s;
      float p = waveReduceSum(s * s);
      if ((tid & 63) == 0) s2p[tG][(tid >> 6) & 1] = p;
    }
    __syncthreads();
    if (tid < T_CAPS) {
      float s2 = s2p[tid][0] + s2p[tid][1];
      float f = (s2 / (1.0f + s2)) * rsqrtf(s2 + 1e-16f);
      f_sh[tid] = f;
      if (iter == 2) out[g * T_CAPS + tid] = sqrtf(f * f * s2 + 1e-16f);
    }
    __syncthreads();
    if (iter == 2) return;
    {  // GEMV2 on raw s; squash factor folded: wv += f*(WT·s), bv += f*(bias·s)
      const unsigned* WTpt = WTp + (tG << 13);
      float s = 0.f;
#pragma unroll 8
      for (int k = 0; k < 64; k++) {
        unsigned u = WTpt[(k << 7) + oG];
        s += s_sh[tG][2 * k] * bf_lo(u) + s_sh[tG][2 * k + 1] * bf_hi(u);
      }
      wv_sh[tG][oG] += f_sh[tG] * s;
      float bp = bias[(tG << 7) + oG] * s_sh[tG][oG];
      bp = waveReduceSum(bp);
      if ((tid & 63) == 0) s2p[tG][(tid >> 6) & 1] = bp;
    }
    __syncthreads();
    if (tid < T_CAPS) bv_sh[tid] += f_sh[tid] * (s2p[tid][0] + s2p[tid][1]);
    __syncthreads();

    float4 acc = make_float4(0.f, 0.f, 0.f, 0.f);
    float cslr = 0.f;
    for (int cb = 0; cb < c; cb += MAXC) {
      int nv = min(MAXC, c - cb);
      for (int n = nL; n < nv; n += 128) {
        const uint4* rowp = aggb4 + (size_t)(st + cb + n) * 16;
        float pr = 0.f;
#pragma unroll 4
        for (int k = 0; k < 16; k++) {
          uint4 u = rowp[k];
          float4 wa = *(const float4*)&wv_sh[tL][k * 8];
          float4 wb = *(const float4*)&wv_sh[tL][k * 8 + 4];
          pr += bf_lo(u.x) * wa.x + bf_hi(u.x) * wa.y + bf_lo(u.y) * wa.z + bf_hi(u.y) * wa.w;
          pr += bf_lo(u.z) * wb.x + bf_hi(u.z) * wb.y + bf_lo(u.w) * wb.z + bf_hi(u.w) * wb.w;
        }
        dt_sh[n][tL] = pr + bv_sh[tL];
      }
      __syncthreads();
      if (tid < nv) {
        float l0 = dt_sh[tid][0], l1 = dt_sh[tid][1], l2 = dt_sh[tid][2], l3 = dt_sh[tid][3];
        float l4 = dt_sh[tid][4], l5 = dt_sh[tid][5], l6 = dt_sh[tid][6], l7 = dt_sh[tid][7];
        float m = fmaxf(fmaxf(fmaxf(l0, l1), fmaxf(l2, l3)),
                        fmaxf(fmaxf(l4, l5), fmaxf(l6, l7)));
        float e0 = __expf(l0 - m), e1 = __expf(l1 - m), e2 = __expf(l2 - m),
              e3 = __expf(l3 - m), e4 = __expf(l4 - m), e5 = __expf(l5 - m),
              e6 = __expf(l6 - m), e7 = __expf(l7 - m);
        float iz = 1.0f / (e0 + e1 + e2 + e3 + e4 + e5 + e6 + e7);
        dt_sh[tid][0] = e0 * iz;
        dt_sh[tid][1] = e1 * iz;
        dt_sh[tid][2] = e2 * iz;
        dt_sh[tid][3] = e3 * iz;
        dt_sh[tid][4] = e4 * iz;
        dt_sh[tid][5] = e5 * iz;
        dt_sh[tid][6] = e6 * iz;
        dt_sh[tid][7] = e7 * iz;
      }
      __syncthreads();
      for (int nj = rep; nj < nv; nj += 4) {
        float cj = dt_sh[nj][tA];
        uint2 u = aggb2[(size_t)(st + cb + nj) * 32 + l32];
        acc.x += cj * bf_lo(u.x);
        acc.y += cj * bf_hi(u.x);
        acc.z += cj * bf_lo(u.y);
        acc.w += cj * bf_hi(u.y);
        if (l32 == 0) cslr += cj;
      }
      __syncthreads();
    }
    int d4 = l32 << 2;
    if (rep > 0) *(float4*)&scratch[(((rep - 1) << 3) + tA) * 128 + d4] = acc;
    if (l32 == 0) csp_sh[tid >> 5] = cslr;
    __syncthreads();
    if (rep == 0) {
#pragma unroll
      for (int m = 0; m < 3; m++) {
        float4 o4 = *(const float4*)&scratch[((m << 3) + tA) * 128 + d4];
        acc.x += o4.x;
        acc.y += o4.y;
        acc.z += o4.z;
        acc.w += o4.w;
      }
      *(float4*)&ac_sh[tA][d4] = acc;
    }
    if (tid < T_CAPS)
      csum_sh[tid] = csp_sh[tid * 4] + csp_sh[tid * 4 + 1] + csp_sh[tid * 4 + 2] +
                     csp_sh[tid * 4 + 3];
    __syncthreads();
  }
}

extern "C" void kernel_launch(void* const* d_in, const int* in_sizes, int n_in, void* d_out,
                              int out_size, void* d_ws, size_t ws_size, hipStream_t stream) {
  const float* x = (const float*)d_in[0];
  const float* ew = (const float*)d_in[1];
  const float* gamma = (const float*)d_in[2];
  const float* beta = (const float*)d_in[3];
  const float* W = (const float*)d_in[4];
  const float* bias = (const float*)d_in[5];
  const int* eidx = (const int*)d_in[6];
  const int* batch = (const int*)d_in[7];
  float* out = (float*)d_out;
  float* w = (float*)d_ws;

  const int* row = eidx;
  const int* col = eidx + N_EDGES;

  int* bcur = (int*)w;                         // 256 (200 used; zeroed in prep)
  int* start = bcur + 256;                     // 260 (even pad)
  float* scale = (float*)(start + 260);        // 128
  float* shift = scale + 128;                  // 128
  float* dis = shift + 128;                    // N
  float* rawxsum = dis + N_NODES;              // 256*128
  float* rawxsq = rawxsum + N_GRAPHS * D_DIM;  // 256*128
  unsigned* Wp = (unsigned*)(rawxsq + N_GRAPHS * D_DIM);  // 65536 (256 KB)
  unsigned* WTp = Wp + 65536;                             // 65536
  int* nstart = (int*)(WTp + 65536);                      // N
  int* ncnt = nstart + N_NODES;                           // N
  uint2* ebuck = (uint2*)(ncnt + N_NODES);                // NBUCK*BCAP*8B
  unsigned* csr = (unsigned*)(ebuck + (size_t)NBUCK * BCAP);            // NBUCK*BCAP*4B
  __hip_bfloat162* y = (__hip_bfloat162*)(csr + (size_t)NBUCK * BCAP);  // N*64
  unsigned* agg_bf = (unsigned*)(y + (size_t)N_NODES * 64);             // N*64

  prep<<<N_NODES / 256, 256, 0, stream>>>(batch, W, start, bcur, Wp, WTp);
  scatter_x<<<300 + N_GRAPHS, 256, 0, stream>>>(row, col, ew, bcur, ebuck, x, start, rawxsum,
                                                rawxsq);
  bn_fin<<<D_DIM, 256, 0, stream>>>(rawxsum, rawxsq, gamma, beta, scale, shift);
  build<<<NBUCK, 256, 0, stream>>>(ebuck, bcur, csr, nstart, ncnt, x, scale, shift, dis, y);
  node_gather<<<N_NODES / 4, 256, 0, stream>>>(y, dis, nstart, ncnt, csr,
                                               (__hip_bfloat162*)agg_bf);
  routing_fused<<<N_GRAPHS, 1024, 0, stream>>>(agg_bf, start, Wp, WTp, bias, rawxsum, scale,
                                               shift, out);
}